// Round 11
// baseline (326.728 us; speedup 1.0000x reference)
//
#include <hip/hip_runtime.h>

// Problem constants (fixed by the reference)
#define B_     32
#define C_IN_  512
#define H_     56
#define W_     56
#define HW_    (H_ * W_)        // 3136
#define C_ENC_ 64
#define K_     256
#define BHW_   (B_ * HW_)       // 100352
#define PTS_ROW_ (3 + C_ENC_)   // 67

#define NCAND_ 640              // candidate slots per batch (512 + tie slack)
#define SCH_   64               // screen: channels per pipeline step
#define SNS_   (C_IN_ / SCH_)   // 8

typedef float f32x4 __attribute__((ext_vector_type(4)));
typedef short bf16x8 __attribute__((ext_vector_type(8)));
typedef unsigned int uint;
typedef unsigned short ushort;

__device__ __forceinline__ ushort f2bf(float f) {     // RNE fp32->bf16
    uint u = __float_as_uint(f);
    return (ushort)((u + 0x7FFFu + ((u >> 16) & 1u)) >> 16);
}

// ---------------------------------------------------------------------------
// k_prep: wt[c][o] fp32 transpose (for exact pass) + wbf[o][c] bf16 (A-frags)
// ---------------------------------------------------------------------------
__global__ __launch_bounds__(256) void k_prep(
        const float* __restrict__ w, float* __restrict__ wt,
        ushort* __restrict__ wbf) {
    int i = blockIdx.x * 256 + threadIdx.x;          // 0 .. 32767
    if (i < C_ENC_ * C_IN_) {
        int o = i / C_IN_;
        int c = i % C_IN_;
        float v = w[i];
        wt[c * C_ENC_ + o] = v;
        wbf[i] = f2bf(v);                            // [o][c] row-major
    }
}

// ---------------------------------------------------------------------------
// k_screen: approximate per-pixel norms via bf16 MFMA (fp32 accumulate).
// Only the CANDIDATE SET depends on this (margin 512 vs needed 256 ~ 60
// sigma); all final outputs are recomputed exactly downstream.
// Block = 256 thr = 4 waves; 64 pixels/block; D = W(bf16) x x(bf16).
//   A (W): lane row=l&15 -> out ot*16+row; k-slots (l>>4)*8+j contiguous
//          -> one 16B load from wbf[out][k0..k0+7] (L1/L2-hot).
//   B (x): staged to LDS px-major bf16 xT[px][c ^ ((px&7)<<3)] (XOR swizzle,
//          write chunks 4-wide / read blocks 8-wide, both 8-aligned-field ->
//          consistent; read elem j == channel cblk+j, verified).
//          One ds_read_b128 per k-step, reused across 4 out-tiles.
//   A/B use the SAME k-slot bijection -> dot products correct regardless of
//   the HW's internal k permutation. C/D: col=l&15(px), row=(l>>4)*4+r (m89).
// Staging: reg loads issued early (T14), cvt+ds_write after vmcnt(0), one
// barrier per step.
// ---------------------------------------------------------------------------
__global__ __launch_bounds__(256) void k_screen(
        const float* __restrict__ F, const ushort* __restrict__ wbf,
        const float* __restrict__ bias, float* __restrict__ napprox) {
    __shared__ ushort xT[2][64][64];                 // 16 KB double buffer

    int t  = threadIdx.x;
    int l  = t & 63;
    int wv = t >> 6;
    int pb = blockIdx.x;                             // 0..1567
    int b  = pb / 49;
    int pixB = (pb % 49) * 64;

    // staging role: thread t -> pixel px (all 64), channel subgroup cg
    int px = t & 63;
    int cg = t >> 6;                                 // 0..3
    const float* fb = F + (size_t)b * C_IN_ * HW_ + pixB + px;
    int swW = (px & 7) << 3;                         // write-side swizzle

    // compute role: wave wv -> pixel group wv*16..+15
    int row = l & 15;                                // A row (out within tile)
    int g   = l >> 4;                                // k-slot group
    int pxl = wv * 16 + (l & 15);                    // B col (pixel)
    int swR = (pxl & 7) << 3;                        // read-side swizzle

    f32x4 acc[4];
    #pragma unroll
    for (int ot = 0; ot < 4; ++ot) acc[ot] = (f32x4){0.f, 0.f, 0.f, 0.f};

    float xr[16];

#define SCREEN_LOAD(S)                                                   \
    _Pragma("unroll") for (int u = 0; u < 4; ++u)                        \
        _Pragma("unroll") for (int i = 0; i < 4; ++i)                    \
            xr[u * 4 + i] =                                              \
                fb[(size_t)((S) * SCH_ + u * 16 + cg * 4 + i) * HW_];

#define SCREEN_WRITE(BUF)                                                \
    _Pragma("unroll") for (int u = 0; u < 4; ++u) {                      \
        int cBase = u * 16 + cg * 4;                                     \
        uint2 pk;                                                        \
        pk.x = (uint)f2bf(xr[u * 4 + 0]) | ((uint)f2bf(xr[u * 4 + 1]) << 16); \
        pk.y = (uint)f2bf(xr[u * 4 + 2]) | ((uint)f2bf(xr[u * 4 + 3]) << 16); \
        *(uint2*)&xT[BUF][px][cBase ^ swW] = pk;                         \
    }

    // prologue: stage step 0
    SCREEN_LOAD(0)
    SCREEN_WRITE(0)
    __syncthreads();

    for (int s = 0; s < SNS_; ++s) {
        if (s + 1 < SNS_) {
            SCREEN_LOAD(s + 1)                        // issue early
            __builtin_amdgcn_sched_barrier(0);        // keep loads up here
        }
        // compute step s from xT[s&1]
        #pragma unroll
        for (int ks = 0; ks < 2; ++ks) {
            int cblk = (ks * 32 + g * 8) ^ swR;
            bf16x8 bfrag = *(const bf16x8*)&xT[s & 1][pxl][cblk];
            #pragma unroll
            for (int ot = 0; ot < 4; ++ot) {
                const ushort* ap = wbf + (size_t)(ot * 16 + row) * C_IN_
                                       + s * SCH_ + ks * 32 + g * 8;
                bf16x8 afrag = *(const bf16x8*)ap;
                acc[ot] = __builtin_amdgcn_mfma_f32_16x16x32_bf16(
                        afrag, bfrag, acc[ot], 0, 0, 0);
            }
        }
        if (s + 1 < SNS_) {
            asm volatile("s_waitcnt vmcnt(0)" ::: "memory");
            SCREEN_WRITE((s + 1) & 1)
        }
        __syncthreads();
    }

    // norm: (D + bias)^2 summed over this lane's 16 outs, then fold the
    // 4 lanes sharing the same pixel column (l^16, l^32).
    float partial = 0.0f;
    #pragma unroll
    for (int ot = 0; ot < 4; ++ot) {
        float4 b4 = *(const float4*)(bias + ot * 16 + g * 4);
        float v0 = acc[ot][0] + b4.x;
        float v1 = acc[ot][1] + b4.y;
        float v2 = acc[ot][2] + b4.z;
        float v3 = acc[ot][3] + b4.w;
        partial = fmaf(v0, v0, partial);
        partial = fmaf(v1, v1, partial);
        partial = fmaf(v2, v2, partial);
        partial = fmaf(v3, v3, partial);
    }
    partial += __shfl_xor(partial, 16);
    partial += __shfl_xor(partial, 32);
    if (l < 16)
        napprox[b * HW_ + pixB + wv * 16 + l] = partial;
}

// ---------------------------------------------------------------------------
// k_sel: radix-select the exact 512th-largest approx norm per batch (clone
// of the 6-round-verified selector, need=512), compact candidate pixel ids
// (>= T, ties included) into cand[b][640], pad with ~0u.
// ---------------------------------------------------------------------------
__global__ __launch_bounds__(512) void k_sel(
        const float* __restrict__ napprox, uint* __restrict__ cand) {
    __shared__ uint keys[HW_];
    __shared__ uint hist[256];
    __shared__ uint s_prefix, s_need, s_cnt;

    int b = blockIdx.x;
    int t = threadIdx.x;
    const float* nb = napprox + b * HW_;

    for (int i = t; i < HW_; i += 512) keys[i] = __float_as_uint(nb[i]);
    if (t == 0) { s_prefix = 0u; s_need = 512u; s_cnt = 0u; }

    for (int r = 0; r < 4; ++r) {
        if (t < 256) hist[t] = 0u;
        __syncthreads();
        uint pfx = s_prefix;
        int shift = 24 - 8 * r;
        for (int i = t; i < HW_; i += 512) {
            uint k = keys[i];
            bool ok = (r == 0) || ((k >> (32 - 8 * r)) == pfx);
            if (ok) atomicAdd(&hist[(k >> shift) & 0xFFu], 1u);
        }
        __syncthreads();
        if (t < 64) {
            uint h0 = hist[4 * t + 0], h1 = hist[4 * t + 1];
            uint h2 = hist[4 * t + 2], h3 = hist[4 * t + 3];
            uint suf = h0 + h1 + h2 + h3;
            #pragma unroll
            for (int off = 1; off < 64; off <<= 1) {
                uint v = __shfl_down(suf, off);
                suf += (t + off < 64) ? v : 0u;
            }
            uint g0 = suf, g1 = suf - h0, g2 = g1 - h1, g3 = g2 - h2,
                 g4 = g3 - h3;
            uint need = s_need;
            if (g0 >= need && g1 < need) { s_prefix = (pfx << 8) | (4u*t+0u); s_need = need - g1; }
            if (g1 >= need && g2 < need) { s_prefix = (pfx << 8) | (4u*t+1u); s_need = need - g2; }
            if (g2 >= need && g3 < need) { s_prefix = (pfx << 8) | (4u*t+2u); s_need = need - g3; }
            if (g3 >= need && g4 < need) { s_prefix = (pfx << 8) | (4u*t+3u); s_need = need - g4; }
        }
        __syncthreads();
    }
    uint T = s_prefix;

    for (int i = t; i < HW_; i += 512) {
        if (keys[i] >= T) {
            uint pos = atomicAdd(&s_cnt, 1u);
            if (pos < NCAND_) cand[b * NCAND_ + pos] = (uint)i;
        }
    }
    __syncthreads();
    for (int i = s_cnt + t; i < NCAND_; i += 512)
        cand[b * NCAND_ + i] = 0xFFFFFFFFu;
}

// ---------------------------------------------------------------------------
// k_exact: exact fp32 conv for candidates (R1/R2-passing structure).
// One wave per slot; lane o; chain = bias then c-ascending fmaf ->
// BIT-IDENTICAL to the original v2 feats/norm chain.
// ---------------------------------------------------------------------------
__global__ __launch_bounds__(64) void k_exact(
        const float* __restrict__ F, const float* __restrict__ wt,
        const float* __restrict__ bias, const uint* __restrict__ cand,
        float* __restrict__ cand_feats) {
    int s = blockIdx.x;                              // global slot
    int b = s / NCAND_;
    int o = threadIdx.x;
    uint p = cand[s];
    if (p == 0xFFFFFFFFu) { cand_feats[(size_t)s * C_ENC_ + o] = 0.0f; return; }

    const float* f = F + (size_t)b * C_IN_ * HW_ + p;
    float acc = bias[o];
    #pragma unroll 8
    for (int c = 0; c < C_IN_; ++c)
        acc = fmaf(f[(size_t)c * HW_], wt[c * C_ENC_ + o], acc);
    cand_feats[(size_t)s * C_ENC_ + o] = acc;
}

// ---------------------------------------------------------------------------
// k_cnorm: exact norms, sequential o=0..63 fmaf chain (the original order).
// ---------------------------------------------------------------------------
__global__ __launch_bounds__(256) void k_cnorm(
        const float* __restrict__ cand_feats, float* __restrict__ cand_norms) {
    int s = blockIdx.x * 256 + threadIdx.x;          // 80*256 == 20480
    const float* fr = cand_feats + (size_t)s * C_ENC_;
    float nrm = 0.0f;
    for (int o = 0; o < C_ENC_; ++o) nrm = fmaf(fr[o], fr[o], nrm);
    cand_norms[s] = nrm;
}

// ---------------------------------------------------------------------------
// k_zero: dense exact-norm plane + pix->slot map init.
// ---------------------------------------------------------------------------
__global__ __launch_bounds__(256) void k_zero(
        float* __restrict__ exn, uint* __restrict__ pix2slot) {
    int i = blockIdx.x * 256 + threadIdx.x;          // 392*256 == 100352
    exn[i] = 0.0f;
    pix2slot[i] = 0u;
}

// ---------------------------------------------------------------------------
// k_scatter: exn[b][p] = exact norm; pix2slot[b][p] = global slot.
// Non-candidates stay 0 (sort last; true top-256 are all candidates).
// ---------------------------------------------------------------------------
__global__ __launch_bounds__(256) void k_scatter(
        const uint* __restrict__ cand, const float* __restrict__ cand_norms,
        float* __restrict__ exn, uint* __restrict__ pix2slot) {
    int s = blockIdx.x * 256 + threadIdx.x;          // 20480
    uint p = cand[s];
    if (p == 0xFFFFFFFFu) return;
    int b = s / NCAND_;
    exn[b * HW_ + p] = cand_norms[s];
    pix2slot[b * HW_ + p] = (uint)s;
}

// ---------------------------------------------------------------------------
// k_topk (VERBATIM, passed R3-R10): radix-select exact 256th-largest,
// compact >= T, bitonic-sort 512 -> exact jax.lax.top_k order + sw plane.
// Input = dense exact norms.
// ---------------------------------------------------------------------------
__global__ __launch_bounds__(512) void k_topk(
        const float* __restrict__ norms, uint* __restrict__ topk,
        float* __restrict__ sw_out) {
    __shared__ uint keys[HW_];
    __shared__ uint hist[256];
    __shared__ unsigned long long sortbuf[512];
    __shared__ uint s_prefix, s_need, s_cnt;
    __shared__ unsigned char flags[HW_];

    int b = blockIdx.x;
    int t = threadIdx.x;
    const float* nb = norms + b * HW_;

    for (int i = t; i < HW_; i += 512) {
        keys[i] = __float_as_uint(nb[i]);
        flags[i] = 0;
    }
    if (t == 0) { s_prefix = 0u; s_need = K_; s_cnt = 0u; }
    for (int i = t; i < 512; i += 512) sortbuf[i] = ~0ULL;

    for (int r = 0; r < 4; ++r) {
        if (t < 256) hist[t] = 0u;
        __syncthreads();
        uint pfx = s_prefix;
        int shift = 24 - 8 * r;
        for (int i = t; i < HW_; i += 512) {
            uint k = keys[i];
            bool ok = (r == 0) || ((k >> (32 - 8 * r)) == pfx);
            if (ok) atomicAdd(&hist[(k >> shift) & 0xFFu], 1u);
        }
        __syncthreads();
        if (t < 64) {
            uint h0 = hist[4 * t + 0], h1 = hist[4 * t + 1];
            uint h2 = hist[4 * t + 2], h3 = hist[4 * t + 3];
            uint suf = h0 + h1 + h2 + h3;
            #pragma unroll
            for (int off = 1; off < 64; off <<= 1) {
                uint v = __shfl_down(suf, off);
                suf += (t + off < 64) ? v : 0u;
            }
            uint g0 = suf, g1 = suf - h0, g2 = g1 - h1, g3 = g2 - h2,
                 g4 = g3 - h3;
            uint need = s_need;
            if (g0 >= need && g1 < need) { s_prefix = (pfx << 8) | (4u*t+0u); s_need = need - g1; }
            if (g1 >= need && g2 < need) { s_prefix = (pfx << 8) | (4u*t+1u); s_need = need - g2; }
            if (g2 >= need && g3 < need) { s_prefix = (pfx << 8) | (4u*t+2u); s_need = need - g3; }
            if (g3 >= need && g4 < need) { s_prefix = (pfx << 8) | (4u*t+3u); s_need = need - g4; }
        }
        __syncthreads();
    }
    uint T = s_prefix;

    for (int i = t; i < HW_; i += 512) {
        uint k = keys[i];
        if (k >= T) {
            uint pos = atomicAdd(&s_cnt, 1u);
            if (pos < 512)
                sortbuf[pos] = ((unsigned long long)(~k) << 32) | (uint)i;
        }
    }
    __syncthreads();

    for (int kk = 2; kk <= 512; kk <<= 1) {
        for (int j = kk >> 1; j > 0; j >>= 1) {
            int ixj = t ^ j;
            if (ixj > t) {
                unsigned long long a = sortbuf[t], c = sortbuf[ixj];
                bool up = ((t & kk) == 0);
                if ((a > c) == up) { sortbuf[t] = c; sortbuf[ixj] = a; }
            }
            __syncthreads();
        }
    }

    if (t < K_) {
        unsigned long long e = sortbuf[t];
        uint idx = (uint)(e & 0xFFFFFFFFu);
        topk[b * K_ + t] = idx;
        flags[idx] = 1;
    }
    __syncthreads();

    float* swb = sw_out + b * HW_;
    for (int i = t; i < HW_; i += 512)
        swb[i] = flags[i] ? 1.0f : 0.0f;
}

// ---------------------------------------------------------------------------
// k_points: rank r row from candidate feats (bit-identical exact values).
// ---------------------------------------------------------------------------
__global__ __launch_bounds__(64) void k_points(
        const float* __restrict__ cand_feats, const uint* __restrict__ pix2slot,
        const uint* __restrict__ topk, float* __restrict__ points) {
    int bk = blockIdx.x;                             // 0 .. B*K-1
    int b = bk >> 8;
    int o = threadIdx.x;
    uint p = topk[bk];
    uint s = pix2slot[b * HW_ + p];

    float v = cand_feats[(size_t)s * C_ENC_ + o];
    float* row = points + (size_t)bk * PTS_ROW_;
    row[3 + o] = v;
    if (o == 0) {
        row[0] = (float)(p % W_);
        row[1] = (float)(p / W_);
        row[2] = 0.0f;
    }
}

// ---------------------------------------------------------------------------
// k_xout: mean over K (k ascending, reference order) of candidate feats.
// ---------------------------------------------------------------------------
__global__ __launch_bounds__(64) void k_xout(
        const float* __restrict__ cand_feats, const uint* __restrict__ pix2slot,
        const uint* __restrict__ topk, float* __restrict__ xout) {
    __shared__ uint sslot[K_];
    int b = blockIdx.x;
    int t = threadIdx.x;
    for (int r = t; r < K_; r += 64)
        sslot[r] = pix2slot[b * HW_ + topk[b * K_ + r]];
    __syncthreads();

    float s = 0.0f;
    #pragma unroll 8
    for (int k = 0; k < K_; ++k)
        s += cand_feats[(size_t)sslot[k] * C_ENC_ + t];
    xout[b * C_ENC_ + t] = s * (1.0f / K_);
}

// ---------------------------------------------------------------------------
extern "C" void kernel_launch(void* const* d_in, const int* in_sizes, int n_in,
                              void* d_out, int out_size, void* d_ws, size_t ws_size,
                              hipStream_t stream) {
    const float* F    = (const float*)d_in[0];       // [B, C_IN, H, W]
    const float* w    = (const float*)d_in[1];       // [C_ENC, C_IN]
    const float* bias = (const float*)d_in[2];       // [C_ENC]

    float* out    = (float*)d_out;
    float* xout   = out;                             // [B, C_ENC]
    float* sw     = out + B_ * C_ENC_;               // [B, 1, H, W]
    float* points = sw + BHW_;                       // [B, K, 67]

    // workspace (~7 MB): all 4-byte types first, bf16 last
    float* wt         = (float*)d_ws;                        // 32768
    float* napprox    = wt + C_IN_ * C_ENC_;                 // 100352
    float* exn        = napprox + BHW_;                      // 100352
    float* cand_feats = exn + BHW_;                          // 20480*64
    float* cand_norms = cand_feats + (size_t)B_ * NCAND_ * C_ENC_; // 20480
    uint*  cand       = (uint*)(cand_norms + B_ * NCAND_);   // 20480
    uint*  pix2slot   = cand + B_ * NCAND_;                  // 100352
    uint*  topk       = pix2slot + BHW_;                     // 8192
    ushort* wbf       = (ushort*)(topk + B_ * K_);           // 32768 ushort

    k_prep   <<<128, 256, 0, stream>>>(w, wt, wbf);
    k_zero   <<<BHW_ / 256, 256, 0, stream>>>(exn, pix2slot);
    k_screen <<<BHW_ / 64, 256, 0, stream>>>(F, wbf, bias, napprox);
    k_sel    <<<B_, 512, 0, stream>>>(napprox, cand);
    k_exact  <<<B_ * NCAND_, 64, 0, stream>>>(F, wt, bias, cand, cand_feats);
    k_cnorm  <<<(B_ * NCAND_) / 256, 256, 0, stream>>>(cand_feats, cand_norms);
    k_scatter<<<(B_ * NCAND_) / 256, 256, 0, stream>>>(cand, cand_norms, exn, pix2slot);
    k_topk   <<<B_, 512, 0, stream>>>(exn, topk, sw);
    k_points <<<B_ * K_, 64, 0, stream>>>(cand_feats, pix2slot, topk, points);
    k_xout   <<<B_, 64, 0, stream>>>(cand_feats, pix2slot, topk, xout);
}

// Round 12
// 256.872 us; speedup vs baseline: 1.2719x; 1.2719x over previous
//
#include <hip/hip_runtime.h>

// Problem constants (fixed by the reference)
#define B_     32
#define C_IN_  512
#define H_     56
#define W_     56
#define HW_    (H_ * W_)        // 3136
#define C_ENC_ 64
#define K_     256
#define BHW_   (B_ * HW_)       // 100352
#define PTS_ROW_ (3 + C_ENC_)   // 67

#define NCAND_ 320              // candidates/batch (top-256 margin >= ~16-30 sigma)
#define SCH_   64               // screen: channels per pipeline step
#define SNS_   (C_IN_ / SCH_)   // 8
#define GCH_   16               // gather: channels per block

typedef float f32x4 __attribute__((ext_vector_type(4)));
typedef short bf16x8 __attribute__((ext_vector_type(8)));
typedef unsigned int uint;
typedef unsigned short ushort;
typedef unsigned long long ull;

__device__ __forceinline__ ushort f2bf(float f) {     // RNE fp32->bf16
    uint u = __float_as_uint(f);
    return (ushort)((u + 0x7FFFu + ((u >> 16) & 1u)) >> 16);
}

// async global->LDS, 16 B per lane; LDS dest must be wave-uniform.
__device__ __forceinline__ void gload_lds16(const float* g, float* l) {
    __builtin_amdgcn_global_load_lds(
        (const __attribute__((address_space(1))) void*)g,
        (__attribute__((address_space(3))) void*)l, 16, 0, 0);
}

// ---------------------------------------------------------------------------
// k_prep: wt[c][o] fp32 (exact pass) + wbf[o][c] bf16 (MFMA A-frags)
// ---------------------------------------------------------------------------
__global__ __launch_bounds__(256) void k_prep(
        const float* __restrict__ w, float* __restrict__ wt,
        ushort* __restrict__ wbf) {
    int i = blockIdx.x * 256 + threadIdx.x;
    if (i < C_ENC_ * C_IN_) {
        int o = i / C_IN_;
        int c = i % C_IN_;
        float v = w[i];
        wt[c * C_ENC_ + o] = v;
        wbf[i] = f2bf(v);
    }
}

// ---------------------------------------------------------------------------
// k_screen (R11-passing MFMA core, staging v2): approx norms via bf16 MFMA.
// Staging: thread (pxq=t&15, chg=t>>4) loads a 4ch x 4px float4 register
// tile (4 loads/step, full 16B/lane — was 16 scalar-ish 4B loads) and writes
// 4 uint2 to the SAME swizzled LDS layout with identical RNE bf16 values ->
// napprox bit-identical to R11 (which passed).
// ---------------------------------------------------------------------------
__global__ __launch_bounds__(256) void k_screen(
        const float* __restrict__ F, const ushort* __restrict__ wbf,
        const float* __restrict__ bias, float* __restrict__ napprox) {
    __shared__ ushort xT[2][64][64];                 // 16 KB double buffer

    int t  = threadIdx.x;
    int l  = t & 63;
    int wv = t >> 6;
    int pb = blockIdx.x;                             // 0..1567
    int b  = pb / 49;
    int pixB = (pb % 49) * 64;

    // staging role: pixel quad pxq (pixels pxq*4..+3), channel group chg*4..+3
    int pxq = t & 15;
    int chg = t >> 4;                                // 0..15
    const float* fb4 = F + (size_t)b * C_IN_ * HW_ + pixB + pxq * 4;

    // compute role (verbatim R11): wave wv -> pixel group wv*16..+15
    int row = l & 15;
    int g   = l >> 4;
    int pxl = wv * 16 + (l & 15);
    int swR = (pxl & 7) << 3;

    f32x4 acc[4];
    #pragma unroll
    for (int ot = 0; ot < 4; ++ot) acc[ot] = (f32x4){0.f, 0.f, 0.f, 0.f};

    float4 xr4[4];

#define SCREEN_LOAD(S)                                                   \
    _Pragma("unroll") for (int u = 0; u < 4; ++u)                        \
        xr4[u] = *(const float4*)(fb4 +                                  \
                 (size_t)((S) * SCH_ + chg * 4 + u) * HW_);

#define SCREEN_WRITE(BUF)                                                \
    _Pragma("unroll") for (int i = 0; i < 4; ++i) {                      \
        int px = pxq * 4 + i;                                            \
        int sw = (px & 7) << 3;                                          \
        uint lo, hi;                                                     \
        asm volatile("v_cvt_pk_bf16_f32 %0, %1, %2" : "=v"(lo)           \
            : "v"(((const float*)&xr4[0])[i]),                           \
              "v"(((const float*)&xr4[1])[i]));                          \
        asm volatile("v_cvt_pk_bf16_f32 %0, %1, %2" : "=v"(hi)           \
            : "v"(((const float*)&xr4[2])[i]),                           \
              "v"(((const float*)&xr4[3])[i]));                          \
        uint2 pk; pk.x = lo; pk.y = hi;                                  \
        *(uint2*)&xT[BUF][px][(chg * 4) ^ sw] = pk;                      \
    }

    SCREEN_LOAD(0)
    SCREEN_WRITE(0)
    __syncthreads();

    for (int s = 0; s < SNS_; ++s) {
        if (s + 1 < SNS_) {
            SCREEN_LOAD(s + 1)
            __builtin_amdgcn_sched_barrier(0);
        }
        #pragma unroll
        for (int ks = 0; ks < 2; ++ks) {
            int cblk = (ks * 32 + g * 8) ^ swR;
            bf16x8 bfrag = *(const bf16x8*)&xT[s & 1][pxl][cblk];
            #pragma unroll
            for (int ot = 0; ot < 4; ++ot) {
                const ushort* ap = wbf + (size_t)(ot * 16 + row) * C_IN_
                                       + s * SCH_ + ks * 32 + g * 8;
                bf16x8 afrag = *(const bf16x8*)ap;
                acc[ot] = __builtin_amdgcn_mfma_f32_16x16x32_bf16(
                        afrag, bfrag, acc[ot], 0, 0, 0);
            }
        }
        if (s + 1 < SNS_) {
            asm volatile("s_waitcnt vmcnt(0)" ::: "memory");
            SCREEN_WRITE((s + 1) & 1)
        }
        __syncthreads();
    }

    float partial = 0.0f;
    #pragma unroll
    for (int ot = 0; ot < 4; ++ot) {
        float4 b4 = *(const float4*)(bias + ot * 16 + g * 4);
        float v0 = acc[ot][0] + b4.x;
        float v1 = acc[ot][1] + b4.y;
        float v2 = acc[ot][2] + b4.z;
        float v3 = acc[ot][3] + b4.w;
        partial = fmaf(v0, v0, partial);
        partial = fmaf(v1, v1, partial);
        partial = fmaf(v2, v2, partial);
        partial = fmaf(v3, v3, partial);
    }
    partial += __shfl_xor(partial, 16);
    partial += __shfl_xor(partial, 32);
    if (l < 16)
        napprox[b * HW_ + pixB + wv * 16 + l] = partial;
}

// ---------------------------------------------------------------------------
// k_sel: radix-select the exact NCAND_-th-largest approx norm per batch
// (verbatim-proven selector, need=NCAND_), compact candidate pixel ids.
// ---------------------------------------------------------------------------
__global__ __launch_bounds__(512) void k_sel(
        const float* __restrict__ napprox, uint* __restrict__ cand) {
    __shared__ uint keys[HW_];
    __shared__ uint hist[256];
    __shared__ uint s_prefix, s_need, s_cnt;

    int b = blockIdx.x;
    int t = threadIdx.x;
    const float* nb = napprox + b * HW_;

    for (int i = t; i < HW_; i += 512) keys[i] = __float_as_uint(nb[i]);
    if (t == 0) { s_prefix = 0u; s_need = (uint)NCAND_; s_cnt = 0u; }

    for (int r = 0; r < 4; ++r) {
        if (t < 256) hist[t] = 0u;
        __syncthreads();
        uint pfx = s_prefix;
        int shift = 24 - 8 * r;
        for (int i = t; i < HW_; i += 512) {
            uint k = keys[i];
            bool ok = (r == 0) || ((k >> (32 - 8 * r)) == pfx);
            if (ok) atomicAdd(&hist[(k >> shift) & 0xFFu], 1u);
        }
        __syncthreads();
        if (t < 64) {
            uint h0 = hist[4 * t + 0], h1 = hist[4 * t + 1];
            uint h2 = hist[4 * t + 2], h3 = hist[4 * t + 3];
            uint suf = h0 + h1 + h2 + h3;
            #pragma unroll
            for (int off = 1; off < 64; off <<= 1) {
                uint v = __shfl_down(suf, off);
                suf += (t + off < 64) ? v : 0u;
            }
            uint g0 = suf, g1 = suf - h0, g2 = g1 - h1, g3 = g2 - h2,
                 g4 = g3 - h3;
            uint need = s_need;
            if (g0 >= need && g1 < need) { s_prefix = (pfx << 8) | (4u*t+0u); s_need = need - g1; }
            if (g1 >= need && g2 < need) { s_prefix = (pfx << 8) | (4u*t+1u); s_need = need - g2; }
            if (g2 >= need && g3 < need) { s_prefix = (pfx << 8) | (4u*t+2u); s_need = need - g3; }
            if (g3 >= need && g4 < need) { s_prefix = (pfx << 8) | (4u*t+3u); s_need = need - g4; }
        }
        __syncthreads();
    }
    uint T = s_prefix;

    for (int i = t; i < HW_; i += 512) {
        if (keys[i] >= T) {
            uint pos = atomicAdd(&s_cnt, 1u);
            if (pos < NCAND_) cand[b * NCAND_ + pos] = (uint)i;
        }
    }
    __syncthreads();
    for (int i = s_cnt + t; i < NCAND_; i += 512)
        cand[b * NCAND_ + i] = 0xFFFFFFFFu;
}

// ---------------------------------------------------------------------------
// k_gather: read F coalesced ONCE, emit compact xg[b][c][s].
// Block per (b, 16-ch chunk): double-buffered gload_lds row staging (issue
// stage(c+1) before gather(c); counted drain after), gather candidates from
// LDS, coalesced 320-dword writes per channel. Fixes k_exact's 525 MB
// scattered FETCH (206 us) -> ~205 MB coalesced.
// ---------------------------------------------------------------------------
__global__ __launch_bounds__(512) void k_gather(
        const float* __restrict__ F, const uint* __restrict__ cand,
        float* __restrict__ xg) {
    __shared__ float rowf[2][HW_];                   // 25 KB
    __shared__ uint scand[NCAND_];

    int t = threadIdx.x;
    int bid = blockIdx.x;                            // 0..1023
    int b = bid >> 5;
    int c0 = (bid & 31) * GCH_;

    for (int i = t; i < NCAND_; i += 512) scand[i] = cand[b * NCAND_ + i];

    const float* src = F + ((size_t)b * C_IN_ + c0) * HW_;
    int wvb = (t >> 6) * 256;                        // wave's float offset
    int ln4 = (t & 63) * 4;

#define G_STAGE(BUF, CI)                                                 \
    {                                                                    \
        const float* sp = src + (size_t)(CI) * HW_;                      \
        gload_lds16(sp + wvb + ln4, &rowf[BUF][wvb]);                    \
        if (2048 + wvb + ln4 < HW_)                                      \
            gload_lds16(sp + 2048 + wvb + ln4, &rowf[BUF][2048 + wvb]);  \
    }

    G_STAGE(0, 0)
    asm volatile("s_waitcnt vmcnt(0)" ::: "memory");
    __syncthreads();

    for (int i = 0; i < GCH_; ++i) {
        if (i + 1 < GCH_) G_STAGE((i + 1) & 1, i + 1)
        // gather channel c0+i from rowf[i&1]; coalesced compact write
        if (t < NCAND_) {
            uint p = scand[t];
            xg[((size_t)b * C_IN_ + c0 + i) * NCAND_ + t] =
                (p == 0xFFFFFFFFu) ? 0.0f : rowf[i & 1][p];
        }
        asm volatile("s_waitcnt vmcnt(0)" ::: "memory");
        __syncthreads();
    }
#undef G_STAGE
}

// ---------------------------------------------------------------------------
// k_exact2: exact fp32 conv for candidates from compact xg (L2-hot).
// Chain = bias then c-ascending fmaf on the SAME gathered F values ->
// cand_feats BIT-IDENTICAL to R11's passing k_exact.
// ---------------------------------------------------------------------------
__global__ __launch_bounds__(64) void k_exact2(
        const float* __restrict__ xg, const float* __restrict__ wt,
        const float* __restrict__ bias, const uint* __restrict__ cand,
        float* __restrict__ cand_feats) {
    int s = blockIdx.x;                              // 0 .. B*NCAND-1
    int b = s / NCAND_;
    int sl = s - b * NCAND_;
    int o = threadIdx.x;
    uint p = cand[s];
    if (p == 0xFFFFFFFFu) { cand_feats[(size_t)s * C_ENC_ + o] = 0.0f; return; }

    const float* xr = xg + (size_t)b * C_IN_ * NCAND_ + sl;
    float acc = bias[o];
    #pragma unroll 8
    for (int c = 0; c < C_IN_; ++c)
        acc = fmaf(xr[(size_t)c * NCAND_], wt[c * C_ENC_ + o], acc);
    cand_feats[(size_t)s * C_ENC_ + o] = acc;
}

// ---------------------------------------------------------------------------
// k_topk2: per batch — exact norms (sequential o=0..63, the original chain),
// bitonic-sort 512 of (~norm)<<32 | pix<<9 | slot (tie-break: pix ascending
// == jax.lax.top_k), emit topk pix+slot, write sw plane.
// Replaces k_zero + k_cnorm + k_scatter + dense k_topk.
// ---------------------------------------------------------------------------
__global__ __launch_bounds__(512) void k_topk2(
        const float* __restrict__ cand_feats, const uint* __restrict__ cand,
        uint* __restrict__ topk_pix, uint* __restrict__ topk_slot,
        float* __restrict__ sw_out) {
    __shared__ ull sortbuf[512];
    __shared__ unsigned char flags[HW_];

    int b = blockIdx.x;
    int t = threadIdx.x;

    for (int i = t; i < HW_; i += 512) flags[i] = 0;

    ull key = ~0ULL;
    if (t < NCAND_) {
        uint p = cand[b * NCAND_ + t];
        if (p != 0xFFFFFFFFu) {
            const float* fr = cand_feats + ((size_t)b * NCAND_ + t) * C_ENC_;
            float nrm = 0.0f;
            for (int o = 0; o < C_ENC_; ++o) nrm = fmaf(fr[o], fr[o], nrm);
            uint nb = __float_as_uint(nrm);
            key = ((ull)(~nb) << 32) | ((ull)(p << 9)) | (ull)(uint)t;
        }
    }
    sortbuf[t] = key;
    __syncthreads();

    for (int kk = 2; kk <= 512; kk <<= 1) {
        for (int j = kk >> 1; j > 0; j >>= 1) {
            int ixj = t ^ j;
            if (ixj > t) {
                ull a = sortbuf[t], c = sortbuf[ixj];
                bool up = ((t & kk) == 0);
                if ((a > c) == up) { sortbuf[t] = c; sortbuf[ixj] = a; }
            }
            __syncthreads();
        }
    }

    if (t < K_) {
        ull e = sortbuf[t];
        uint low = (uint)e;
        uint pix = low >> 9;
        uint sl  = low & 511u;
        topk_pix[b * K_ + t]  = pix;
        topk_slot[b * K_ + t] = sl;
        flags[pix] = 1;
    }
    __syncthreads();

    float* swb = sw_out + b * HW_;
    for (int i = t; i < HW_; i += 512)
        swb[i] = flags[i] ? 1.0f : 0.0f;
}

// ---------------------------------------------------------------------------
// k_points: rank row from candidate feats (bit-identical exact values).
// ---------------------------------------------------------------------------
__global__ __launch_bounds__(64) void k_points(
        const float* __restrict__ cand_feats, const uint* __restrict__ topk_pix,
        const uint* __restrict__ topk_slot, float* __restrict__ points) {
    int bk = blockIdx.x;
    int b = bk >> 8;
    int o = threadIdx.x;
    uint p  = topk_pix[bk];
    uint sl = topk_slot[bk];

    float v = cand_feats[((size_t)b * NCAND_ + sl) * C_ENC_ + o];
    float* row = points + (size_t)bk * PTS_ROW_;
    row[3 + o] = v;
    if (o == 0) {
        row[0] = (float)(p % W_);
        row[1] = (float)(p / W_);
        row[2] = 0.0f;
    }
}

// ---------------------------------------------------------------------------
// k_xout: mean over K (k ascending, reference order) of candidate feats.
// ---------------------------------------------------------------------------
__global__ __launch_bounds__(64) void k_xout(
        const float* __restrict__ cand_feats, const uint* __restrict__ topk_slot,
        float* __restrict__ xout) {
    __shared__ uint sslot[K_];
    int b = blockIdx.x;
    int t = threadIdx.x;
    for (int r = t; r < K_; r += 64) sslot[r] = topk_slot[b * K_ + r];
    __syncthreads();

    float s = 0.0f;
    #pragma unroll 8
    for (int k = 0; k < K_; ++k)
        s += cand_feats[((size_t)b * NCAND_ + sslot[k]) * C_ENC_ + t];
    xout[b * C_ENC_ + t] = s * (1.0f / K_);
}

// ---------------------------------------------------------------------------
extern "C" void kernel_launch(void* const* d_in, const int* in_sizes, int n_in,
                              void* d_out, int out_size, void* d_ws, size_t ws_size,
                              hipStream_t stream) {
    const float* F    = (const float*)d_in[0];       // [B, C_IN, H, W]
    const float* w    = (const float*)d_in[1];       // [C_ENC, C_IN]
    const float* bias = (const float*)d_in[2];       // [C_ENC]

    float* out    = (float*)d_out;
    float* xout   = out;                             // [B, C_ENC]
    float* sw     = out + B_ * C_ENC_;               // [B, 1, H, W]
    float* points = sw + BHW_;                       // [B, K, 67]

    // workspace (~24.3 MB, under the 26+ MB proven in R4-R10)
    float* wt         = (float*)d_ws;                        // 32768 f
    float* napprox    = wt + C_IN_ * C_ENC_;                 // 100352 f
    float* xg         = napprox + BHW_;                      // 32*512*320 f
    float* cand_feats = xg + (size_t)B_ * C_IN_ * NCAND_;    // 10240*64 f
    uint*  cand       = (uint*)(cand_feats + (size_t)B_ * NCAND_ * C_ENC_);
    uint*  topk_pix   = cand + B_ * NCAND_;                  // 8192
    uint*  topk_slot  = topk_pix + B_ * K_;                  // 8192
    ushort* wbf       = (ushort*)(topk_slot + B_ * K_);      // 32768 us

    k_prep   <<<128, 256, 0, stream>>>(w, wt, wbf);
    k_screen <<<BHW_ / 64, 256, 0, stream>>>(F, wbf, bias, napprox);
    k_sel    <<<B_, 512, 0, stream>>>(napprox, cand);
    k_gather <<<B_ * (C_IN_ / GCH_), 512, 0, stream>>>(F, cand, xg);
    k_exact2 <<<B_ * NCAND_, 64, 0, stream>>>(xg, wt, bias, cand, cand_feats);
    k_topk2  <<<B_, 512, 0, stream>>>(cand_feats, cand, topk_pix, topk_slot, sw);
    k_points <<<B_ * K_, 64, 0, stream>>>(cand_feats, topk_pix, topk_slot, points);
    k_xout   <<<B_, 64, 0, stream>>>(cand_feats, topk_slot, xout);
}

// Round 13
// 183.287 us; speedup vs baseline: 1.7826x; 1.4015x over previous
//
#include <hip/hip_runtime.h>

// Problem constants (fixed by the reference)
#define B_     32
#define C_IN_  512
#define H_     56
#define W_     56
#define HW_    (H_ * W_)        // 3136
#define C_ENC_ 64
#define K_     256
#define BHW_   (B_ * HW_)       // 100352
#define PTS_ROW_ (3 + C_ENC_)   // 67

#define NCAND_ 320              // candidates/batch (top-256 margin >= ~16-30 sigma)
#define SCH_   64               // screen: channels per pipeline step
#define SNS_   (C_IN_ / SCH_)   // 8
#define GCH_   16               // gather: channels per block
#define STILE_ 64               // exact2: slots per block
#define NTILE_ (NCAND_ / STILE_) // 5

typedef float f32x4 __attribute__((ext_vector_type(4)));
typedef short bf16x8 __attribute__((ext_vector_type(8)));
typedef unsigned int uint;
typedef unsigned short ushort;
typedef unsigned long long ull;

__device__ __forceinline__ ushort f2bf(float f) {     // RNE fp32->bf16
    uint u = __float_as_uint(f);
    return (ushort)((u + 0x7FFFu + ((u >> 16) & 1u)) >> 16);
}

// async global->LDS, 16 B per lane; LDS dest must be wave-uniform.
__device__ __forceinline__ void gload_lds16(const float* g, float* l) {
    __builtin_amdgcn_global_load_lds(
        (const __attribute__((address_space(1))) void*)g,
        (__attribute__((address_space(3))) void*)l, 16, 0, 0);
}

// ---------------------------------------------------------------------------
// k_prep: wt[c][o] fp32 (exact pass) + wbf[o][c] bf16 (MFMA A-frags)
// ---------------------------------------------------------------------------
__global__ __launch_bounds__(256) void k_prep(
        const float* __restrict__ w, float* __restrict__ wt,
        ushort* __restrict__ wbf) {
    int i = blockIdx.x * 256 + threadIdx.x;
    if (i < C_ENC_ * C_IN_) {
        int o = i / C_IN_;
        int c = i % C_IN_;
        float v = w[i];
        wt[c * C_ENC_ + o] = v;
        wbf[i] = f2bf(v);
    }
}

// ---------------------------------------------------------------------------
// k_screen (passed R11/R12): approx norms via bf16 MFMA. Unchanged.
// ---------------------------------------------------------------------------
__global__ __launch_bounds__(256) void k_screen(
        const float* __restrict__ F, const ushort* __restrict__ wbf,
        const float* __restrict__ bias, float* __restrict__ napprox) {
    __shared__ ushort xT[2][64][64];                 // 16 KB double buffer

    int t  = threadIdx.x;
    int l  = t & 63;
    int wv = t >> 6;
    int pb = blockIdx.x;                             // 0..1567
    int b  = pb / 49;
    int pixB = (pb % 49) * 64;

    int pxq = t & 15;
    int chg = t >> 4;                                // 0..15
    const float* fb4 = F + (size_t)b * C_IN_ * HW_ + pixB + pxq * 4;

    int row = l & 15;
    int g   = l >> 4;
    int pxl = wv * 16 + (l & 15);
    int swR = (pxl & 7) << 3;

    f32x4 acc[4];
    #pragma unroll
    for (int ot = 0; ot < 4; ++ot) acc[ot] = (f32x4){0.f, 0.f, 0.f, 0.f};

    float4 xr4[4];

#define SCREEN_LOAD(S)                                                   \
    _Pragma("unroll") for (int u = 0; u < 4; ++u)                        \
        xr4[u] = *(const float4*)(fb4 +                                  \
                 (size_t)((S) * SCH_ + chg * 4 + u) * HW_);

#define SCREEN_WRITE(BUF)                                                \
    _Pragma("unroll") for (int i = 0; i < 4; ++i) {                      \
        int px = pxq * 4 + i;                                            \
        int sw = (px & 7) << 3;                                          \
        uint lo, hi;                                                     \
        asm volatile("v_cvt_pk_bf16_f32 %0, %1, %2" : "=v"(lo)           \
            : "v"(((const float*)&xr4[0])[i]),                           \
              "v"(((const float*)&xr4[1])[i]));                          \
        asm volatile("v_cvt_pk_bf16_f32 %0, %1, %2" : "=v"(hi)           \
            : "v"(((const float*)&xr4[2])[i]),                           \
              "v"(((const float*)&xr4[3])[i]));                          \
        uint2 pk; pk.x = lo; pk.y = hi;                                  \
        *(uint2*)&xT[BUF][px][(chg * 4) ^ sw] = pk;                      \
    }

    SCREEN_LOAD(0)
    SCREEN_WRITE(0)
    __syncthreads();

    for (int s = 0; s < SNS_; ++s) {
        if (s + 1 < SNS_) {
            SCREEN_LOAD(s + 1)
            __builtin_amdgcn_sched_barrier(0);
        }
        #pragma unroll
        for (int ks = 0; ks < 2; ++ks) {
            int cblk = (ks * 32 + g * 8) ^ swR;
            bf16x8 bfrag = *(const bf16x8*)&xT[s & 1][pxl][cblk];
            #pragma unroll
            for (int ot = 0; ot < 4; ++ot) {
                const ushort* ap = wbf + (size_t)(ot * 16 + row) * C_IN_
                                       + s * SCH_ + ks * 32 + g * 8;
                bf16x8 afrag = *(const bf16x8*)ap;
                acc[ot] = __builtin_amdgcn_mfma_f32_16x16x32_bf16(
                        afrag, bfrag, acc[ot], 0, 0, 0);
            }
        }
        if (s + 1 < SNS_) {
            asm volatile("s_waitcnt vmcnt(0)" ::: "memory");
            SCREEN_WRITE((s + 1) & 1)
        }
        __syncthreads();
    }

    float partial = 0.0f;
    #pragma unroll
    for (int ot = 0; ot < 4; ++ot) {
        float4 b4 = *(const float4*)(bias + ot * 16 + g * 4);
        float v0 = acc[ot][0] + b4.x;
        float v1 = acc[ot][1] + b4.y;
        float v2 = acc[ot][2] + b4.z;
        float v3 = acc[ot][3] + b4.w;
        partial = fmaf(v0, v0, partial);
        partial = fmaf(v1, v1, partial);
        partial = fmaf(v2, v2, partial);
        partial = fmaf(v3, v3, partial);
    }
    partial += __shfl_xor(partial, 16);
    partial += __shfl_xor(partial, 32);
    if (l < 16)
        napprox[b * HW_ + pixB + wv * 16 + l] = partial;
}

// ---------------------------------------------------------------------------
// k_sel (passed R11/R12): radix-select NCAND_-th-largest approx norm,
// compact candidate pixel ids. Unchanged.
// ---------------------------------------------------------------------------
__global__ __launch_bounds__(512) void k_sel(
        const float* __restrict__ napprox, uint* __restrict__ cand) {
    __shared__ uint keys[HW_];
    __shared__ uint hist[256];
    __shared__ uint s_prefix, s_need, s_cnt;

    int b = blockIdx.x;
    int t = threadIdx.x;
    const float* nb = napprox + b * HW_;

    for (int i = t; i < HW_; i += 512) keys[i] = __float_as_uint(nb[i]);
    if (t == 0) { s_prefix = 0u; s_need = (uint)NCAND_; s_cnt = 0u; }

    for (int r = 0; r < 4; ++r) {
        if (t < 256) hist[t] = 0u;
        __syncthreads();
        uint pfx = s_prefix;
        int shift = 24 - 8 * r;
        for (int i = t; i < HW_; i += 512) {
            uint k = keys[i];
            bool ok = (r == 0) || ((k >> (32 - 8 * r)) == pfx);
            if (ok) atomicAdd(&hist[(k >> shift) & 0xFFu], 1u);
        }
        __syncthreads();
        if (t < 64) {
            uint h0 = hist[4 * t + 0], h1 = hist[4 * t + 1];
            uint h2 = hist[4 * t + 2], h3 = hist[4 * t + 3];
            uint suf = h0 + h1 + h2 + h3;
            #pragma unroll
            for (int off = 1; off < 64; off <<= 1) {
                uint v = __shfl_down(suf, off);
                suf += (t + off < 64) ? v : 0u;
            }
            uint g0 = suf, g1 = suf - h0, g2 = g1 - h1, g3 = g2 - h2,
                 g4 = g3 - h3;
            uint need = s_need;
            if (g0 >= need && g1 < need) { s_prefix = (pfx << 8) | (4u*t+0u); s_need = need - g1; }
            if (g1 >= need && g2 < need) { s_prefix = (pfx << 8) | (4u*t+1u); s_need = need - g2; }
            if (g2 >= need && g3 < need) { s_prefix = (pfx << 8) | (4u*t+2u); s_need = need - g3; }
            if (g3 >= need && g4 < need) { s_prefix = (pfx << 8) | (4u*t+3u); s_need = need - g4; }
        }
        __syncthreads();
    }
    uint T = s_prefix;

    for (int i = t; i < HW_; i += 512) {
        if (keys[i] >= T) {
            uint pos = atomicAdd(&s_cnt, 1u);
            if (pos < NCAND_) cand[b * NCAND_ + pos] = (uint)i;
        }
    }
    __syncthreads();
    for (int i = s_cnt + t; i < NCAND_; i += 512)
        cand[b * NCAND_ + i] = 0xFFFFFFFFu;
}

// ---------------------------------------------------------------------------
// k_gather (passed R12): read F coalesced once, emit compact xg[b][c][s].
// ---------------------------------------------------------------------------
__global__ __launch_bounds__(512) void k_gather(
        const float* __restrict__ F, const uint* __restrict__ cand,
        float* __restrict__ xg) {
    __shared__ float rowf[2][HW_];                   // 25 KB
    __shared__ uint scand[NCAND_];

    int t = threadIdx.x;
    int bid = blockIdx.x;                            // 0..1023
    int b = bid >> 5;
    int c0 = (bid & 31) * GCH_;

    for (int i = t; i < NCAND_; i += 512) scand[i] = cand[b * NCAND_ + i];

    const float* src = F + ((size_t)b * C_IN_ + c0) * HW_;
    int wvb = (t >> 6) * 256;
    int ln4 = (t & 63) * 4;

#define G_STAGE(BUF, CI)                                                 \
    {                                                                    \
        const float* sp = src + (size_t)(CI) * HW_;                      \
        gload_lds16(sp + wvb + ln4, &rowf[BUF][wvb]);                    \
        if (2048 + wvb + ln4 < HW_)                                      \
            gload_lds16(sp + 2048 + wvb + ln4, &rowf[BUF][2048 + wvb]);  \
    }

    G_STAGE(0, 0)
    asm volatile("s_waitcnt vmcnt(0)" ::: "memory");
    __syncthreads();

    for (int i = 0; i < GCH_; ++i) {
        if (i + 1 < GCH_) G_STAGE((i + 1) & 1, i + 1)
        if (t < NCAND_) {
            uint p = scand[t];
            xg[((size_t)b * C_IN_ + c0 + i) * NCAND_ + t] =
                (p == 0xFFFFFFFFu) ? 0.0f : rowf[i & 1][p];
        }
        asm volatile("s_waitcnt vmcnt(0)" ::: "memory");
        __syncthreads();
    }
#undef G_STAGE
}

// ---------------------------------------------------------------------------
// k_exact2 v3: tiled exact conv. Block per (b, 64-slot tile): 256 thr =
// 64 slots x 4 out-groups (R2-passing shape). Wave reads 64 CONSECUTIVE
// slots at fixed c -> coalesced 256B; each block's xg slice is disjoint ->
// xg fetched ~once (fixes R12's 197MB XCD-multiplied broadcast re-fetch).
// Chain = bias then c-ascending fmaf on the same gathered values ->
// cand_feats BIT-IDENTICAL to R11/R12's passing exact pass.
// ---------------------------------------------------------------------------
__global__ __launch_bounds__(256) void k_exact2(
        const float* __restrict__ xg, const float* __restrict__ wt,
        const float* __restrict__ bias, float* __restrict__ cand_feats) {
    int bid = blockIdx.x;                            // 0..159
    int b = bid / NTILE_;
    int tile = bid - b * NTILE_;
    int t = threadIdx.x;
    int sl = tile * STILE_ + (t & 63);
    int g = __builtin_amdgcn_readfirstlane(t >> 6);  // 0..3

    const float* xr = xg + (size_t)b * C_IN_ * NCAND_ + sl;
    const float* wg = wt + g * 16;

    float acc[16];
    #pragma unroll
    for (int o = 0; o < 16; ++o) acc[o] = bias[g * 16 + o];

    #pragma unroll 4
    for (int c = 0; c < C_IN_; ++c) {
        float x = xr[(size_t)c * NCAND_];
        #pragma unroll
        for (int o = 0; o < 16; ++o)
            acc[o] = fmaf(x, wg[c * C_ENC_ + o], acc[o]);
    }

    float* fo = cand_feats + ((size_t)b * NCAND_ + sl) * C_ENC_ + g * 16;
    #pragma unroll
    for (int o = 0; o < 16; ++o) fo[o] = acc[o];
}

// ---------------------------------------------------------------------------
// k_topk2 (passed R12): exact norms (sequential o chain) + bitonic-512 of
// (~norm)<<32 | pix<<9 | slot -> exact jax order; sw plane. Unchanged.
// ---------------------------------------------------------------------------
__global__ __launch_bounds__(512) void k_topk2(
        const float* __restrict__ cand_feats, const uint* __restrict__ cand,
        uint* __restrict__ topk_pix, uint* __restrict__ topk_slot,
        float* __restrict__ sw_out) {
    __shared__ ull sortbuf[512];
    __shared__ unsigned char flags[HW_];

    int b = blockIdx.x;
    int t = threadIdx.x;

    for (int i = t; i < HW_; i += 512) flags[i] = 0;

    ull key = ~0ULL;
    if (t < NCAND_) {
        uint p = cand[b * NCAND_ + t];
        if (p != 0xFFFFFFFFu) {
            const float* fr = cand_feats + ((size_t)b * NCAND_ + t) * C_ENC_;
            float nrm = 0.0f;
            for (int o = 0; o < C_ENC_; ++o) nrm = fmaf(fr[o], fr[o], nrm);
            uint nb = __float_as_uint(nrm);
            key = ((ull)(~nb) << 32) | ((ull)(p << 9)) | (ull)(uint)t;
        }
    }
    sortbuf[t] = key;
    __syncthreads();

    for (int kk = 2; kk <= 512; kk <<= 1) {
        for (int j = kk >> 1; j > 0; j >>= 1) {
            int ixj = t ^ j;
            if (ixj > t) {
                ull a = sortbuf[t], c = sortbuf[ixj];
                bool up = ((t & kk) == 0);
                if ((a > c) == up) { sortbuf[t] = c; sortbuf[ixj] = a; }
            }
            __syncthreads();
        }
    }

    if (t < K_) {
        ull e = sortbuf[t];
        uint low = (uint)e;
        uint pix = low >> 9;
        uint sl  = low & 511u;
        topk_pix[b * K_ + t]  = pix;
        topk_slot[b * K_ + t] = sl;
        flags[pix] = 1;
    }
    __syncthreads();

    float* swb = sw_out + b * HW_;
    for (int i = t; i < HW_; i += 512)
        swb[i] = flags[i] ? 1.0f : 0.0f;
}

// ---------------------------------------------------------------------------
// k_points (passed R12): rank row from candidate feats.
// ---------------------------------------------------------------------------
__global__ __launch_bounds__(64) void k_points(
        const float* __restrict__ cand_feats, const uint* __restrict__ topk_pix,
        const uint* __restrict__ topk_slot, float* __restrict__ points) {
    int bk = blockIdx.x;
    int b = bk >> 8;
    int o = threadIdx.x;
    uint p  = topk_pix[bk];
    uint sl = topk_slot[bk];

    float v = cand_feats[((size_t)b * NCAND_ + sl) * C_ENC_ + o];
    float* row = points + (size_t)bk * PTS_ROW_;
    row[3 + o] = v;
    if (o == 0) {
        row[0] = (float)(p % W_);
        row[1] = (float)(p / W_);
        row[2] = 0.0f;
    }
}

// ---------------------------------------------------------------------------
// k_xout (passed R12): mean over K (k ascending) of candidate feats.
// ---------------------------------------------------------------------------
__global__ __launch_bounds__(64) void k_xout(
        const float* __restrict__ cand_feats, const uint* __restrict__ topk_slot,
        float* __restrict__ xout) {
    __shared__ uint sslot[K_];
    int b = blockIdx.x;
    int t = threadIdx.x;
    for (int r = t; r < K_; r += 64) sslot[r] = topk_slot[b * K_ + r];
    __syncthreads();

    float s = 0.0f;
    #pragma unroll 8
    for (int k = 0; k < K_; ++k)
        s += cand_feats[((size_t)b * NCAND_ + sslot[k]) * C_ENC_ + t];
    xout[b * C_ENC_ + t] = s * (1.0f / K_);
}

// ---------------------------------------------------------------------------
extern "C" void kernel_launch(void* const* d_in, const int* in_sizes, int n_in,
                              void* d_out, int out_size, void* d_ws, size_t ws_size,
                              hipStream_t stream) {
    const float* F    = (const float*)d_in[0];       // [B, C_IN, H, W]
    const float* w    = (const float*)d_in[1];       // [C_ENC, C_IN]
    const float* bias = (const float*)d_in[2];       // [C_ENC]

    float* out    = (float*)d_out;
    float* xout   = out;                             // [B, C_ENC]
    float* sw     = out + B_ * C_ENC_;               // [B, 1, H, W]
    float* points = sw + BHW_;                       // [B, K, 67]

    float* wt         = (float*)d_ws;                        // 32768 f
    float* napprox    = wt + C_IN_ * C_ENC_;                 // 100352 f
    float* xg         = napprox + BHW_;                      // 32*512*320 f
    float* cand_feats = xg + (size_t)B_ * C_IN_ * NCAND_;    // 10240*64 f
    uint*  cand       = (uint*)(cand_feats + (size_t)B_ * NCAND_ * C_ENC_);
    uint*  topk_pix   = cand + B_ * NCAND_;                  // 8192
    uint*  topk_slot  = topk_pix + B_ * K_;                  // 8192
    ushort* wbf       = (ushort*)(topk_slot + B_ * K_);      // 32768 us

    k_prep   <<<128, 256, 0, stream>>>(w, wt, wbf);
    k_screen <<<BHW_ / 64, 256, 0, stream>>>(F, wbf, bias, napprox);
    k_sel    <<<B_, 512, 0, stream>>>(napprox, cand);
    k_gather <<<B_ * (C_IN_ / GCH_), 512, 0, stream>>>(F, cand, xg);
    k_exact2 <<<B_ * NTILE_, 256, 0, stream>>>(xg, wt, bias, cand_feats);
    k_topk2  <<<B_, 512, 0, stream>>>(cand_feats, cand, topk_pix, topk_slot, sw);
    k_points <<<B_ * K_, 64, 0, stream>>>(cand_feats, topk_pix, topk_slot, points);
    k_xout   <<<B_, 64, 0, stream>>>(cand_feats, topk_slot, xout);
}

// Round 14
// 176.127 us; speedup vs baseline: 1.8551x; 1.0407x over previous
//
#include <hip/hip_runtime.h>

// Problem constants (fixed by the reference)
#define B_     32
#define C_IN_  512
#define H_     56
#define W_     56
#define HW_    (H_ * W_)        // 3136
#define C_ENC_ 64
#define K_     256
#define BHW_   (B_ * HW_)       // 100352
#define PTS_ROW_ (3 + C_ENC_)   // 67

#define NCAND_ 320              // candidates/batch (top-256 margin >= ~16-30 sigma)
#define SCH_   64               // screen: channels per pipeline step
#define SNS_   (C_IN_ / SCH_)   // 8
#define GCH_   16               // gather: channels per block
#define STILE_ 64               // exact2: slots per block
#define NTILE_ (NCAND_ / STILE_) // 5
#define ECH_   64               // exact2: channels per pipeline step
#define ENS_   (C_IN_ / ECH_)   // 8

typedef float f32x4 __attribute__((ext_vector_type(4)));
typedef short bf16x8 __attribute__((ext_vector_type(8)));
typedef unsigned int uint;
typedef unsigned short ushort;
typedef unsigned long long ull;

__device__ __forceinline__ ushort f2bf(float f) {     // RNE fp32->bf16
    uint u = __float_as_uint(f);
    return (ushort)((u + 0x7FFFu + ((u >> 16) & 1u)) >> 16);
}

// async global->LDS, 16 B per lane; LDS dest must be wave-uniform.
__device__ __forceinline__ void gload_lds16(const float* g, float* l) {
    __builtin_amdgcn_global_load_lds(
        (const __attribute__((address_space(1))) void*)g,
        (__attribute__((address_space(3))) void*)l, 16, 0, 0);
}

// ---------------------------------------------------------------------------
// k_prep: wt[c][o] fp32 (exact pass) + wbf[o][c] bf16 (MFMA A-frags)
// ---------------------------------------------------------------------------
__global__ __launch_bounds__(256) void k_prep(
        const float* __restrict__ w, float* __restrict__ wt,
        ushort* __restrict__ wbf) {
    int i = blockIdx.x * 256 + threadIdx.x;
    if (i < C_ENC_ * C_IN_) {
        int o = i / C_IN_;
        int c = i % C_IN_;
        float v = w[i];
        wt[c * C_ENC_ + o] = v;
        wbf[i] = f2bf(v);
    }
}

// ---------------------------------------------------------------------------
// k_screen (passed R11-R13): approx norms via bf16 MFMA. FROZEN.
// ---------------------------------------------------------------------------
__global__ __launch_bounds__(256) void k_screen(
        const float* __restrict__ F, const ushort* __restrict__ wbf,
        const float* __restrict__ bias, float* __restrict__ napprox) {
    __shared__ ushort xT[2][64][64];                 // 16 KB double buffer

    int t  = threadIdx.x;
    int l  = t & 63;
    int wv = t >> 6;
    int pb = blockIdx.x;                             // 0..1567
    int b  = pb / 49;
    int pixB = (pb % 49) * 64;

    int pxq = t & 15;
    int chg = t >> 4;                                // 0..15
    const float* fb4 = F + (size_t)b * C_IN_ * HW_ + pixB + pxq * 4;

    int row = l & 15;
    int g   = l >> 4;
    int pxl = wv * 16 + (l & 15);
    int swR = (pxl & 7) << 3;

    f32x4 acc[4];
    #pragma unroll
    for (int ot = 0; ot < 4; ++ot) acc[ot] = (f32x4){0.f, 0.f, 0.f, 0.f};

    float4 xr4[4];

#define SCREEN_LOAD(S)                                                   \
    _Pragma("unroll") for (int u = 0; u < 4; ++u)                        \
        xr4[u] = *(const float4*)(fb4 +                                  \
                 (size_t)((S) * SCH_ + chg * 4 + u) * HW_);

#define SCREEN_WRITE(BUF)                                                \
    _Pragma("unroll") for (int i = 0; i < 4; ++i) {                      \
        int px = pxq * 4 + i;                                            \
        int sw = (px & 7) << 3;                                          \
        uint lo, hi;                                                     \
        asm volatile("v_cvt_pk_bf16_f32 %0, %1, %2" : "=v"(lo)           \
            : "v"(((const float*)&xr4[0])[i]),                           \
              "v"(((const float*)&xr4[1])[i]));                          \
        asm volatile("v_cvt_pk_bf16_f32 %0, %1, %2" : "=v"(hi)           \
            : "v"(((const float*)&xr4[2])[i]),                           \
              "v"(((const float*)&xr4[3])[i]));                          \
        uint2 pk; pk.x = lo; pk.y = hi;                                  \
        *(uint2*)&xT[BUF][px][(chg * 4) ^ sw] = pk;                      \
    }

    SCREEN_LOAD(0)
    SCREEN_WRITE(0)
    __syncthreads();

    for (int s = 0; s < SNS_; ++s) {
        if (s + 1 < SNS_) {
            SCREEN_LOAD(s + 1)
            __builtin_amdgcn_sched_barrier(0);
        }
        #pragma unroll
        for (int ks = 0; ks < 2; ++ks) {
            int cblk = (ks * 32 + g * 8) ^ swR;
            bf16x8 bfrag = *(const bf16x8*)&xT[s & 1][pxl][cblk];
            #pragma unroll
            for (int ot = 0; ot < 4; ++ot) {
                const ushort* ap = wbf + (size_t)(ot * 16 + row) * C_IN_
                                       + s * SCH_ + ks * 32 + g * 8;
                bf16x8 afrag = *(const bf16x8*)ap;
                acc[ot] = __builtin_amdgcn_mfma_f32_16x16x32_bf16(
                        afrag, bfrag, acc[ot], 0, 0, 0);
            }
        }
        if (s + 1 < SNS_) {
            asm volatile("s_waitcnt vmcnt(0)" ::: "memory");
            SCREEN_WRITE((s + 1) & 1)
        }
        __syncthreads();
    }

    float partial = 0.0f;
    #pragma unroll
    for (int ot = 0; ot < 4; ++ot) {
        float4 b4 = *(const float4*)(bias + ot * 16 + g * 4);
        float v0 = acc[ot][0] + b4.x;
        float v1 = acc[ot][1] + b4.y;
        float v2 = acc[ot][2] + b4.z;
        float v3 = acc[ot][3] + b4.w;
        partial = fmaf(v0, v0, partial);
        partial = fmaf(v1, v1, partial);
        partial = fmaf(v2, v2, partial);
        partial = fmaf(v3, v3, partial);
    }
    partial += __shfl_xor(partial, 16);
    partial += __shfl_xor(partial, 32);
    if (l < 16)
        napprox[b * HW_ + pixB + wv * 16 + l] = partial;
}

// ---------------------------------------------------------------------------
// k_sel (passed R11-R13): radix-select NCAND_-th-largest approx norm. FROZEN.
// ---------------------------------------------------------------------------
__global__ __launch_bounds__(512) void k_sel(
        const float* __restrict__ napprox, uint* __restrict__ cand) {
    __shared__ uint keys[HW_];
    __shared__ uint hist[256];
    __shared__ uint s_prefix, s_need, s_cnt;

    int b = blockIdx.x;
    int t = threadIdx.x;
    const float* nb = napprox + b * HW_;

    for (int i = t; i < HW_; i += 512) keys[i] = __float_as_uint(nb[i]);
    if (t == 0) { s_prefix = 0u; s_need = (uint)NCAND_; s_cnt = 0u; }

    for (int r = 0; r < 4; ++r) {
        if (t < 256) hist[t] = 0u;
        __syncthreads();
        uint pfx = s_prefix;
        int shift = 24 - 8 * r;
        for (int i = t; i < HW_; i += 512) {
            uint k = keys[i];
            bool ok = (r == 0) || ((k >> (32 - 8 * r)) == pfx);
            if (ok) atomicAdd(&hist[(k >> shift) & 0xFFu], 1u);
        }
        __syncthreads();
        if (t < 64) {
            uint h0 = hist[4 * t + 0], h1 = hist[4 * t + 1];
            uint h2 = hist[4 * t + 2], h3 = hist[4 * t + 3];
            uint suf = h0 + h1 + h2 + h3;
            #pragma unroll
            for (int off = 1; off < 64; off <<= 1) {
                uint v = __shfl_down(suf, off);
                suf += (t + off < 64) ? v : 0u;
            }
            uint g0 = suf, g1 = suf - h0, g2 = g1 - h1, g3 = g2 - h2,
                 g4 = g3 - h3;
            uint need = s_need;
            if (g0 >= need && g1 < need) { s_prefix = (pfx << 8) | (4u*t+0u); s_need = need - g1; }
            if (g1 >= need && g2 < need) { s_prefix = (pfx << 8) | (4u*t+1u); s_need = need - g2; }
            if (g2 >= need && g3 < need) { s_prefix = (pfx << 8) | (4u*t+2u); s_need = need - g3; }
            if (g3 >= need && g4 < need) { s_prefix = (pfx << 8) | (4u*t+3u); s_need = need - g4; }
        }
        __syncthreads();
    }
    uint T = s_prefix;

    for (int i = t; i < HW_; i += 512) {
        if (keys[i] >= T) {
            uint pos = atomicAdd(&s_cnt, 1u);
            if (pos < NCAND_) cand[b * NCAND_ + pos] = (uint)i;
        }
    }
    __syncthreads();
    for (int i = s_cnt + t; i < NCAND_; i += 512)
        cand[b * NCAND_ + i] = 0xFFFFFFFFu;
}

// ---------------------------------------------------------------------------
// k_gather (passed R12/R13): read F coalesced once -> xg[b][c][s]. FROZEN.
// ---------------------------------------------------------------------------
__global__ __launch_bounds__(512) void k_gather(
        const float* __restrict__ F, const uint* __restrict__ cand,
        float* __restrict__ xg) {
    __shared__ float rowf[2][HW_];                   // 25 KB
    __shared__ uint scand[NCAND_];

    int t = threadIdx.x;
    int bid = blockIdx.x;                            // 0..1023
    int b = bid >> 5;
    int c0 = (bid & 31) * GCH_;

    for (int i = t; i < NCAND_; i += 512) scand[i] = cand[b * NCAND_ + i];

    const float* src = F + ((size_t)b * C_IN_ + c0) * HW_;
    int wvb = (t >> 6) * 256;
    int ln4 = (t & 63) * 4;

#define G_STAGE(BUF, CI)                                                 \
    {                                                                    \
        const float* sp = src + (size_t)(CI) * HW_;                      \
        gload_lds16(sp + wvb + ln4, &rowf[BUF][wvb]);                    \
        if (2048 + wvb + ln4 < HW_)                                      \
            gload_lds16(sp + 2048 + wvb + ln4, &rowf[BUF][2048 + wvb]);  \
    }

    G_STAGE(0, 0)
    asm volatile("s_waitcnt vmcnt(0)" ::: "memory");
    __syncthreads();

    for (int i = 0; i < GCH_; ++i) {
        if (i + 1 < GCH_) G_STAGE((i + 1) & 1, i + 1)
        if (t < NCAND_) {
            uint p = scand[t];
            xg[((size_t)b * C_IN_ + c0 + i) * NCAND_ + t] =
                (p == 0xFFFFFFFFu) ? 0.0f : rowf[i & 1][p];
        }
        asm volatile("s_waitcnt vmcnt(0)" ::: "memory");
        __syncthreads();
    }
#undef G_STAGE
}

// ---------------------------------------------------------------------------
// k_exact2 v4: v8-proven LDS pipeline. R13's v3 ran ~54us: 160 blocks x
// 4 waves = 1 wave/SIMD, per-c global loads fully latency-exposed. v4
// stages xg tiles via gload_lds16 double-buffer (intra-wave pipelining,
// v8 structure = 137us at 100352 px -> ~14us at 10240 slots):
//   block (b, 64-slot tile); step = 64 channels; wave wv stages its 16
//   channels (4 x 16B instrs: lane l -> c +(l>>4), slots (l&15)*4..+3,
//   LDS dest linear [ch][slot]); compute: ds_read_b32 (64 contiguous
//   lanes, conflict-free) + 16 fmaf per channel.
// Chain = bias then c-ascending fmaf -> cand_feats BIT-IDENTICAL to
// R11/R12/R13's passing exact pass -> identical selection.
// ---------------------------------------------------------------------------
__global__ __launch_bounds__(256) void k_exact2(
        const float* __restrict__ xg, const float* __restrict__ wt,
        const float* __restrict__ bias, float* __restrict__ cand_feats) {
    __shared__ float xb[2][ECH_][STILE_];            // 32 KB double buffer

    int bid = blockIdx.x;                            // 0..159
    int b = bid / NTILE_;
    int tile = bid - b * NTILE_;
    int t = threadIdx.x;
    int l = t & 63;                                  // slot lane
    int g = __builtin_amdgcn_readfirstlane(t >> 6);  // out-group & stage-group

    // staging source: lane l -> channel +(l>>4), slot bytes (l&15)*16
    const float* gs = xg + ((size_t)b * C_IN_) * NCAND_ + tile * STILE_
                         + (size_t)(l >> 4) * NCAND_ + (l & 15) * 4;
    const float* wg = wt + g * 16;

    float acc[16];
    #pragma unroll
    for (int o = 0; o < 16; ++o) acc[o] = bias[g * 16 + o];

    // prologue: stage step 0 — wave g stages channels g*16..+15
    #pragma unroll
    for (int u = 0; u < 4; ++u)
        gload_lds16(gs + (size_t)(g * 16 + u * 4) * NCAND_,
                    &xb[0][g * 16 + u * 4][0]);
    asm volatile("s_waitcnt vmcnt(0)" ::: "memory");
    __syncthreads();

    for (int s = 0; s < ENS_; ++s) {
        if (s + 1 < ENS_) {
            int cn = (s + 1) * ECH_ + g * 16;
            float* dst = &xb[(s + 1) & 1][g * 16][0];
            #pragma unroll
            for (int u = 0; u < 4; ++u)
                gload_lds16(gs + (size_t)(cn + u * 4) * NCAND_,
                            dst + u * 4 * STILE_);
        }
        {
            int cb = s * ECH_;
            #pragma unroll 8
            for (int cl = 0; cl < ECH_; ++cl) {
                float x = xb[s & 1][cl][l];
                #pragma unroll
                for (int o = 0; o < 16; ++o)
                    acc[o] = fmaf(x, wg[(cb + cl) * C_ENC_ + o], acc[o]);
            }
        }
        asm volatile("s_waitcnt vmcnt(0)" ::: "memory");
        __syncthreads();
    }

    float* fo = cand_feats + ((size_t)b * NCAND_ + tile * STILE_ + l) * C_ENC_
              + g * 16;
    #pragma unroll
    for (int o = 0; o < 16; ++o) fo[o] = acc[o];
}

// ---------------------------------------------------------------------------
// k_topk2 (passed R12/R13): exact norms (sequential o chain) + bitonic-512
// of (~norm)<<32 | pix<<9 | slot -> exact jax order; sw plane. FROZEN.
// ---------------------------------------------------------------------------
__global__ __launch_bounds__(512) void k_topk2(
        const float* __restrict__ cand_feats, const uint* __restrict__ cand,
        uint* __restrict__ topk_pix, uint* __restrict__ topk_slot,
        float* __restrict__ sw_out) {
    __shared__ ull sortbuf[512];
    __shared__ unsigned char flags[HW_];

    int b = blockIdx.x;
    int t = threadIdx.x;

    for (int i = t; i < HW_; i += 512) flags[i] = 0;

    ull key = ~0ULL;
    if (t < NCAND_) {
        uint p = cand[b * NCAND_ + t];
        if (p != 0xFFFFFFFFu) {
            const float* fr = cand_feats + ((size_t)b * NCAND_ + t) * C_ENC_;
            float nrm = 0.0f;
            for (int o = 0; o < C_ENC_; ++o) nrm = fmaf(fr[o], fr[o], nrm);
            uint nb = __float_as_uint(nrm);
            key = ((ull)(~nb) << 32) | ((ull)(p << 9)) | (ull)(uint)t;
        }
    }
    sortbuf[t] = key;
    __syncthreads();

    for (int kk = 2; kk <= 512; kk <<= 1) {
        for (int j = kk >> 1; j > 0; j >>= 1) {
            int ixj = t ^ j;
            if (ixj > t) {
                ull a = sortbuf[t], c = sortbuf[ixj];
                bool up = ((t & kk) == 0);
                if ((a > c) == up) { sortbuf[t] = c; sortbuf[ixj] = a; }
            }
            __syncthreads();
        }
    }

    if (t < K_) {
        ull e = sortbuf[t];
        uint low = (uint)e;
        uint pix = low >> 9;
        uint sl  = low & 511u;
        topk_pix[b * K_ + t]  = pix;
        topk_slot[b * K_ + t] = sl;
        flags[pix] = 1;
    }
    __syncthreads();

    float* swb = sw_out + b * HW_;
    for (int i = t; i < HW_; i += 512)
        swb[i] = flags[i] ? 1.0f : 0.0f;
}

// ---------------------------------------------------------------------------
// k_points (passed R12/R13): rank row from candidate feats. FROZEN.
// ---------------------------------------------------------------------------
__global__ __launch_bounds__(64) void k_points(
        const float* __restrict__ cand_feats, const uint* __restrict__ topk_pix,
        const uint* __restrict__ topk_slot, float* __restrict__ points) {
    int bk = blockIdx.x;
    int b = bk >> 8;
    int o = threadIdx.x;
    uint p  = topk_pix[bk];
    uint sl = topk_slot[bk];

    float v = cand_feats[((size_t)b * NCAND_ + sl) * C_ENC_ + o];
    float* row = points + (size_t)bk * PTS_ROW_;
    row[3 + o] = v;
    if (o == 0) {
        row[0] = (float)(p % W_);
        row[1] = (float)(p / W_);
        row[2] = 0.0f;
    }
}

// ---------------------------------------------------------------------------
// k_xout (passed R12/R13): mean over K (k ascending). FROZEN.
// ---------------------------------------------------------------------------
__global__ __launch_bounds__(64) void k_xout(
        const float* __restrict__ cand_feats, const uint* __restrict__ topk_slot,
        float* __restrict__ xout) {
    __shared__ uint sslot[K_];
    int b = blockIdx.x;
    int t = threadIdx.x;
    for (int r = t; r < K_; r += 64) sslot[r] = topk_slot[b * K_ + r];
    __syncthreads();

    float s = 0.0f;
    #pragma unroll 8
    for (int k = 0; k < K_; ++k)
        s += cand_feats[((size_t)b * NCAND_ + sslot[k]) * C_ENC_ + t];
    xout[b * C_ENC_ + t] = s * (1.0f / K_);
}

// ---------------------------------------------------------------------------
extern "C" void kernel_launch(void* const* d_in, const int* in_sizes, int n_in,
                              void* d_out, int out_size, void* d_ws, size_t ws_size,
                              hipStream_t stream) {
    const float* F    = (const float*)d_in[0];       // [B, C_IN, H, W]
    const float* w    = (const float*)d_in[1];       // [C_ENC, C_IN]
    const float* bias = (const float*)d_in[2];       // [C_ENC]

    float* out    = (float*)d_out;
    float* xout   = out;                             // [B, C_ENC]
    float* sw     = out + B_ * C_ENC_;               // [B, 1, H, W]
    float* points = sw + BHW_;                       // [B, K, 67]

    float* wt         = (float*)d_ws;                        // 32768 f
    float* napprox    = wt + C_IN_ * C_ENC_;                 // 100352 f
    float* xg         = napprox + BHW_;                      // 32*512*320 f
    float* cand_feats = xg + (size_t)B_ * C_IN_ * NCAND_;    // 10240*64 f
    uint*  cand       = (uint*)(cand_feats + (size_t)B_ * NCAND_ * C_ENC_);
    uint*  topk_pix   = cand + B_ * NCAND_;                  // 8192
    uint*  topk_slot  = topk_pix + B_ * K_;                  // 8192
    ushort* wbf       = (ushort*)(topk_slot + B_ * K_);      // 32768 us

    k_prep   <<<128, 256, 0, stream>>>(w, wt, wbf);
    k_screen <<<BHW_ / 64, 256, 0, stream>>>(F, wbf, bias, napprox);
    k_sel    <<<B_, 512, 0, stream>>>(napprox, cand);
    k_gather <<<B_ * (C_IN_ / GCH_), 512, 0, stream>>>(F, cand, xg);
    k_exact2 <<<B_ * NTILE_, 256, 0, stream>>>(xg, wt, bias, cand_feats);
    k_topk2  <<<B_, 512, 0, stream>>>(cand_feats, cand, topk_pix, topk_slot, sw);
    k_points <<<B_ * K_, 64, 0, stream>>>(cand_feats, topk_pix, topk_slot, points);
    k_xout   <<<B_, 64, 0, stream>>>(cand_feats, topk_slot, xout);
}

// Round 16
// 175.264 us; speedup vs baseline: 1.8642x; 1.0049x over previous
//
#include <hip/hip_runtime.h>

// Problem constants (fixed by the reference)
#define B_     32
#define C_IN_  512
#define H_     56
#define W_     56
#define HW_    (H_ * W_)        // 3136
#define C_ENC_ 64
#define K_     256
#define BHW_   (B_ * HW_)       // 100352
#define PTS_ROW_ (3 + C_ENC_)   // 67

#define NCAND_ 320              // candidates/batch (top-256 margin >= ~16-30 sigma)
#define SCH_   64               // screen: channels per pipeline step
#define SNS_   (C_IN_ / SCH_)   // 8
#define GCH_   16               // gather: channels per block
#define STILE_ 64               // exact2: slots per block
#define NTILE_ (NCAND_ / STILE_) // 5
#define ECH_   64               // exact2: channels per pipeline step
#define ENS_   (C_IN_ / ECH_)   // 8

typedef float f32x4 __attribute__((ext_vector_type(4)));
typedef short bf16x8 __attribute__((ext_vector_type(8)));
typedef unsigned int uint;
typedef unsigned short ushort;
typedef unsigned long long ull;

__device__ __forceinline__ ushort f2bf(float f) {     // RNE fp32->bf16
    uint u = __float_as_uint(f);
    return (ushort)((u + 0x7FFFu + ((u >> 16) & 1u)) >> 16);
}

// async global->LDS, 16 B per lane; LDS dest must be wave-uniform.
__device__ __forceinline__ void gload_lds16(const float* g, float* l) {
    __builtin_amdgcn_global_load_lds(
        (const __attribute__((address_space(1))) void*)g,
        (__attribute__((address_space(3))) void*)l, 16, 0, 0);
}

// ---------------------------------------------------------------------------
// k_prep: wt[c][o] fp32 (exact pass) + wbf[o][c] bf16 (MFMA A-frags)
// ---------------------------------------------------------------------------
__global__ __launch_bounds__(256) void k_prep(
        const float* __restrict__ w, float* __restrict__ wt,
        ushort* __restrict__ wbf) {
    int i = blockIdx.x * 256 + threadIdx.x;
    if (i < C_ENC_ * C_IN_) {
        int o = i / C_IN_;
        int c = i % C_IN_;
        float v = w[i];
        wt[c * C_ENC_ + o] = v;
        wbf[i] = f2bf(v);
    }
}

// ---------------------------------------------------------------------------
// k_screen v2 (from R15 — races re-traced clean; R15's failure was k_gather's
// counted-vmcnt bug, see below): same math as R11-R14, napprox bit-identical
// (identical RNE cvt + identical MFMA sequence). Pipeline fix: afrags issued
// FIRST each step (so afrag vmcnt waits never drain newer x-loads); x-loads
// prefetched one full step ahead in static reg banks xrA/xrB (loop unrolled
// x2, no runtime ring index).
// ---------------------------------------------------------------------------
__global__ __launch_bounds__(256) void k_screen(
        const float* __restrict__ F, const ushort* __restrict__ wbf,
        const float* __restrict__ bias, float* __restrict__ napprox) {
    __shared__ ushort xT[2][64][64];                 // 16 KB double buffer

    int t  = threadIdx.x;
    int l  = t & 63;
    int wv = t >> 6;
    int pb = blockIdx.x;                             // 0..1567
    int b  = pb / 49;
    int pixB = (pb % 49) * 64;

    int pxq = t & 15;
    int chg = t >> 4;                                // 0..15
    const float* fb4 = F + (size_t)b * C_IN_ * HW_ + pixB + pxq * 4;

    int row = l & 15;
    int g   = l >> 4;
    int pxl = wv * 16 + (l & 15);
    int swR = (pxl & 7) << 3;

    f32x4 acc[4];
    #pragma unroll
    for (int ot = 0; ot < 4; ++ot) acc[ot] = (f32x4){0.f, 0.f, 0.f, 0.f};

    float4 xrA[4], xrB[4];
    bf16x8 af[2][4];

#define SCREEN_LOAD(BANK, S)                                             \
    _Pragma("unroll") for (int u = 0; u < 4; ++u)                        \
        BANK[u] = *(const float4*)(fb4 +                                 \
                 (size_t)((S) * SCH_ + chg * 4 + u) * HW_);

#define SCREEN_WRITE(BANK, BUF)                                          \
    _Pragma("unroll") for (int i = 0; i < 4; ++i) {                      \
        int px = pxq * 4 + i;                                            \
        int sw = (px & 7) << 3;                                          \
        uint lo, hi;                                                     \
        asm volatile("v_cvt_pk_bf16_f32 %0, %1, %2" : "=v"(lo)           \
            : "v"(((const float*)&BANK[0])[i]),                          \
              "v"(((const float*)&BANK[1])[i]));                         \
        asm volatile("v_cvt_pk_bf16_f32 %0, %1, %2" : "=v"(hi)           \
            : "v"(((const float*)&BANK[2])[i]),                          \
              "v"(((const float*)&BANK[3])[i]));                         \
        uint2 pk; pk.x = lo; pk.y = hi;                                  \
        *(uint2*)&xT[BUF][px][(chg * 4) ^ sw] = pk;                      \
    }

#define AFRAG_LOAD(S)                                                    \
    _Pragma("unroll") for (int ks = 0; ks < 2; ++ks)                     \
        _Pragma("unroll") for (int ot = 0; ot < 4; ++ot)                 \
            af[ks][ot] = *(const bf16x8*)(wbf +                          \
                (size_t)(ot * 16 + row) * C_IN_ + (S) * SCH_ + ks * 32 + g * 8);

#define SCREEN_MFMA(S)                                                   \
    _Pragma("unroll") for (int ks = 0; ks < 2; ++ks) {                   \
        int cblk = (ks * 32 + g * 8) ^ swR;                              \
        bf16x8 bfrag = *(const bf16x8*)&xT[(S) & 1][pxl][cblk];          \
        _Pragma("unroll") for (int ot = 0; ot < 4; ++ot)                 \
            acc[ot] = __builtin_amdgcn_mfma_f32_16x16x32_bf16(           \
                    af[ks][ot], bfrag, acc[ot], 0, 0, 0);                \
    }

    // prologue: x(0) -> xT[0]; x(1) loaded into xrB (stays in regs)
    SCREEN_LOAD(xrA, 0)
    SCREEN_LOAD(xrB, 1)
    SCREEN_WRITE(xrA, 0)                             // compiler waits xrA only
    __syncthreads();

    for (int sp = 0; sp < SNS_; sp += 2) {
        // even step sp: compute xT[0]; write x(sp+1)=xrB; load x(sp+2)->xrA
        AFRAG_LOAD(sp)
        __builtin_amdgcn_sched_barrier(0);
        if (sp + 2 < SNS_) { SCREEN_LOAD(xrA, sp + 2) }
        __builtin_amdgcn_sched_barrier(0);
        SCREEN_MFMA(sp)
        SCREEN_WRITE(xrB, 1)
        __syncthreads();
        // odd step sp+1: compute xT[1]; write x(sp+2)=xrA; load x(sp+3)->xrB
        AFRAG_LOAD(sp + 1)
        __builtin_amdgcn_sched_barrier(0);
        if (sp + 3 < SNS_) { SCREEN_LOAD(xrB, sp + 3) }
        __builtin_amdgcn_sched_barrier(0);
        SCREEN_MFMA(sp + 1)
        if (sp + 2 < SNS_) { SCREEN_WRITE(xrA, 0) }
        __syncthreads();
    }

    float partial = 0.0f;
    #pragma unroll
    for (int ot = 0; ot < 4; ++ot) {
        float4 b4 = *(const float4*)(bias + ot * 16 + g * 4);
        float v0 = acc[ot][0] + b4.x;
        float v1 = acc[ot][1] + b4.y;
        float v2 = acc[ot][2] + b4.z;
        float v3 = acc[ot][3] + b4.w;
        partial = fmaf(v0, v0, partial);
        partial = fmaf(v1, v1, partial);
        partial = fmaf(v2, v2, partial);
        partial = fmaf(v3, v3, partial);
    }
    partial += __shfl_xor(partial, 16);
    partial += __shfl_xor(partial, 32);
    if (l < 16)
        napprox[b * HW_ + pixB + wv * 16 + l] = partial;
}

// ---------------------------------------------------------------------------
// k_sel (passed R11-R15): radix-select NCAND_-th-largest approx norm. FROZEN.
// ---------------------------------------------------------------------------
__global__ __launch_bounds__(512) void k_sel(
        const float* __restrict__ napprox, uint* __restrict__ cand) {
    __shared__ uint keys[HW_];
    __shared__ uint hist[256];
    __shared__ uint s_prefix, s_need, s_cnt;

    int b = blockIdx.x;
    int t = threadIdx.x;
    const float* nb = napprox + b * HW_;

    for (int i = t; i < HW_; i += 512) keys[i] = __float_as_uint(nb[i]);
    if (t == 0) { s_prefix = 0u; s_need = (uint)NCAND_; s_cnt = 0u; }

    for (int r = 0; r < 4; ++r) {
        if (t < 256) hist[t] = 0u;
        __syncthreads();
        uint pfx = s_prefix;
        int shift = 24 - 8 * r;
        for (int i = t; i < HW_; i += 512) {
            uint k = keys[i];
            bool ok = (r == 0) || ((k >> (32 - 8 * r)) == pfx);
            if (ok) atomicAdd(&hist[(k >> shift) & 0xFFu], 1u);
        }
        __syncthreads();
        if (t < 64) {
            uint h0 = hist[4 * t + 0], h1 = hist[4 * t + 1];
            uint h2 = hist[4 * t + 2], h3 = hist[4 * t + 3];
            uint suf = h0 + h1 + h2 + h3;
            #pragma unroll
            for (int off = 1; off < 64; off <<= 1) {
                uint v = __shfl_down(suf, off);
                suf += (t + off < 64) ? v : 0u;
            }
            uint g0 = suf, g1 = suf - h0, g2 = g1 - h1, g3 = g2 - h2,
                 g4 = g3 - h3;
            uint need = s_need;
            if (g0 >= need && g1 < need) { s_prefix = (pfx << 8) | (4u*t+0u); s_need = need - g1; }
            if (g1 >= need && g2 < need) { s_prefix = (pfx << 8) | (4u*t+1u); s_need = need - g2; }
            if (g2 >= need && g3 < need) { s_prefix = (pfx << 8) | (4u*t+2u); s_need = need - g3; }
            if (g3 >= need && g4 < need) { s_prefix = (pfx << 8) | (4u*t+3u); s_need = need - g4; }
        }
        __syncthreads();
    }
    uint T = s_prefix;

    for (int i = t; i < HW_; i += 512) {
        if (keys[i] >= T) {
            uint pos = atomicAdd(&s_cnt, 1u);
            if (pos < NCAND_) cand[b * NCAND_ + pos] = (uint)i;
        }
    }
    __syncthreads();
    for (int i = s_cnt + t; i < NCAND_; i += 512)
        cand[b * NCAND_ + i] = 0xFFFFFFFFu;
}

// ---------------------------------------------------------------------------
// k_gather — REVERTED VERBATIM to the R12-R14 passing version. R15's counted
// vmcnt(3) was wrong twice: (a) off-by-one (4 loads outstanding; vmcnt(3)
// leaves stage(i+1)'s 2nd load un-landed); (b) the HW_ tail guard makes
// waves 5-7 issue 1 load/stage (and the xg store also counts) -> no fixed
// count is right for all waves. vmcnt(0) is immune to both.
// ---------------------------------------------------------------------------
__global__ __launch_bounds__(512) void k_gather(
        const float* __restrict__ F, const uint* __restrict__ cand,
        float* __restrict__ xg) {
    __shared__ float rowf[2][HW_];                   // 25 KB
    __shared__ uint scand[NCAND_];

    int t = threadIdx.x;
    int bid = blockIdx.x;                            // 0..1023
    int b = bid >> 5;
    int c0 = (bid & 31) * GCH_;

    for (int i = t; i < NCAND_; i += 512) scand[i] = cand[b * NCAND_ + i];

    const float* src = F + ((size_t)b * C_IN_ + c0) * HW_;
    int wvb = (t >> 6) * 256;
    int ln4 = (t & 63) * 4;

#define G_STAGE(BUF, CI)                                                 \
    {                                                                    \
        const float* sp = src + (size_t)(CI) * HW_;                      \
        gload_lds16(sp + wvb + ln4, &rowf[BUF][wvb]);                    \
        if (2048 + wvb + ln4 < HW_)                                      \
            gload_lds16(sp + 2048 + wvb + ln4, &rowf[BUF][2048 + wvb]);  \
    }

    G_STAGE(0, 0)
    asm volatile("s_waitcnt vmcnt(0)" ::: "memory");
    __syncthreads();

    for (int i = 0; i < GCH_; ++i) {
        if (i + 1 < GCH_) G_STAGE((i + 1) & 1, i + 1)
        if (t < NCAND_) {
            uint p = scand[t];
            xg[((size_t)b * C_IN_ + c0 + i) * NCAND_ + t] =
                (p == 0xFFFFFFFFu) ? 0.0f : rowf[i & 1][p];
        }
        asm volatile("s_waitcnt vmcnt(0)" ::: "memory");
        __syncthreads();
    }
#undef G_STAGE
}

// ---------------------------------------------------------------------------
// k_exact2 (passed R14, verbatim): v8-style LDS pipeline. cand_feats
// BIT-IDENTICAL chain (bias then c-ascending fmaf). FROZEN.
// ---------------------------------------------------------------------------
__global__ __launch_bounds__(256) void k_exact2(
        const float* __restrict__ xg, const float* __restrict__ wt,
        const float* __restrict__ bias, float* __restrict__ cand_feats) {
    __shared__ float xb[2][ECH_][STILE_];            // 32 KB double buffer

    int bid = blockIdx.x;                            // 0..159
    int b = bid / NTILE_;
    int tile = bid - b * NTILE_;
    int t = threadIdx.x;
    int l = t & 63;
    int g = __builtin_amdgcn_readfirstlane(t >> 6);

    const float* gs = xg + ((size_t)b * C_IN_) * NCAND_ + tile * STILE_
                         + (size_t)(l >> 4) * NCAND_ + (l & 15) * 4;
    const float* wg = wt + g * 16;

    float acc[16];
    #pragma unroll
    for (int o = 0; o < 16; ++o) acc[o] = bias[g * 16 + o];

    #pragma unroll
    for (int u = 0; u < 4; ++u)
        gload_lds16(gs + (size_t)(g * 16 + u * 4) * NCAND_,
                    &xb[0][g * 16 + u * 4][0]);
    asm volatile("s_waitcnt vmcnt(0)" ::: "memory");
    __syncthreads();

    for (int s = 0; s < ENS_; ++s) {
        if (s + 1 < ENS_) {
            int cn = (s + 1) * ECH_ + g * 16;
            float* dst = &xb[(s + 1) & 1][g * 16][0];
            #pragma unroll
            for (int u = 0; u < 4; ++u)
                gload_lds16(gs + (size_t)(cn + u * 4) * NCAND_,
                            dst + u * 4 * STILE_);
        }
        {
            int cb = s * ECH_;
            #pragma unroll 8
            for (int cl = 0; cl < ECH_; ++cl) {
                float x = xb[s & 1][cl][l];
                #pragma unroll
                for (int o = 0; o < 16; ++o)
                    acc[o] = fmaf(x, wg[(cb + cl) * C_ENC_ + o], acc[o]);
            }
        }
        asm volatile("s_waitcnt vmcnt(0)" ::: "memory");
        __syncthreads();
    }

    float* fo = cand_feats + ((size_t)b * NCAND_ + tile * STILE_ + l) * C_ENC_
              + g * 16;
    #pragma unroll
    for (int o = 0; o < 16; ++o) fo[o] = acc[o];
}

// ---------------------------------------------------------------------------
// k_final (from R15): topk2 (VERBATIM selection logic, passed R12-R14) +
// points + xout fused (saves 2 launches).
// ---------------------------------------------------------------------------
__global__ __launch_bounds__(512) void k_final(
        const float* __restrict__ cand_feats, const uint* __restrict__ cand,
        float* __restrict__ sw_out, float* __restrict__ points,
        float* __restrict__ xout) {
    __shared__ ull sortbuf[512];
    __shared__ unsigned char flags[HW_];
    __shared__ uint spix[K_];
    __shared__ uint sslot[K_];

    int b = blockIdx.x;
    int t = threadIdx.x;

    for (int i = t; i < HW_; i += 512) flags[i] = 0;

    ull key = ~0ULL;
    if (t < NCAND_) {
        uint p = cand[b * NCAND_ + t];
        if (p != 0xFFFFFFFFu) {
            const float* fr = cand_feats + ((size_t)b * NCAND_ + t) * C_ENC_;
            float nrm = 0.0f;
            for (int o = 0; o < C_ENC_; ++o) nrm = fmaf(fr[o], fr[o], nrm);
            uint nb = __float_as_uint(nrm);
            key = ((ull)(~nb) << 32) | ((ull)(p << 9)) | (ull)(uint)t;
        }
    }
    sortbuf[t] = key;
    __syncthreads();

    for (int kk = 2; kk <= 512; kk <<= 1) {
        for (int j = kk >> 1; j > 0; j >>= 1) {
            int ixj = t ^ j;
            if (ixj > t) {
                ull a = sortbuf[t], c = sortbuf[ixj];
                bool up = ((t & kk) == 0);
                if ((a > c) == up) { sortbuf[t] = c; sortbuf[ixj] = a; }
            }
            __syncthreads();
        }
    }

    if (t < K_) {
        ull e = sortbuf[t];
        uint low = (uint)e;
        uint pix = low >> 9;
        uint sl  = low & 511u;
        spix[t] = pix;
        sslot[t] = sl;
        flags[pix] = 1;
    }
    __syncthreads();

    // sw plane
    float* swb = sw_out + b * HW_;
    for (int i = t; i < HW_; i += 512)
        swb[i] = flags[i] ? 1.0f : 0.0f;

    // points: thread t < 256 writes rank-t row
    if (t < K_) {
        uint p  = spix[t];
        uint sl = sslot[t];
        const float* fr = cand_feats + ((size_t)b * NCAND_ + sl) * C_ENC_;
        float* row = points + (size_t)(b * K_ + t) * PTS_ROW_;
        row[0] = (float)(p % W_);
        row[1] = (float)(p / W_);
        row[2] = 0.0f;
        #pragma unroll 8
        for (int o = 0; o < C_ENC_; ++o) row[3 + o] = fr[o];
    }

    // xout: threads 0..63, mean over K (k ascending = reference order)
    if (t < C_ENC_) {
        float s = 0.0f;
        #pragma unroll 8
        for (int k = 0; k < K_; ++k)
            s += cand_feats[((size_t)b * NCAND_ + sslot[k]) * C_ENC_ + t];
        xout[b * C_ENC_ + t] = s * (1.0f / K_);
    }
}

// ---------------------------------------------------------------------------
extern "C" void kernel_launch(void* const* d_in, const int* in_sizes, int n_in,
                              void* d_out, int out_size, void* d_ws, size_t ws_size,
                              hipStream_t stream) {
    const float* F    = (const float*)d_in[0];       // [B, C_IN, H, W]
    const float* w    = (const float*)d_in[1];       // [C_ENC, C_IN]
    const float* bias = (const float*)d_in[2];       // [C_ENC]

    float* out    = (float*)d_out;
    float* xout   = out;                             // [B, C_ENC]
    float* sw     = out + B_ * C_ENC_;               // [B, 1, H, W]
    float* points = sw + BHW_;                       // [B, K, 67]

    float* wt         = (float*)d_ws;                        // 32768 f
    float* napprox    = wt + C_IN_ * C_ENC_;                 // 100352 f
    float* xg         = napprox + BHW_;                      // 32*512*320 f
    float* cand_feats = xg + (size_t)B_ * C_IN_ * NCAND_;    // 10240*64 f
    uint*  cand       = (uint*)(cand_feats + (size_t)B_ * NCAND_ * C_ENC_);
    ushort* wbf       = (ushort*)(cand + B_ * NCAND_);       // 32768 us

    k_prep   <<<128, 256, 0, stream>>>(w, wt, wbf);
    k_screen <<<BHW_ / 64, 256, 0, stream>>>(F, wbf, bias, napprox);
    k_sel    <<<B_, 512, 0, stream>>>(napprox, cand);
    k_gather <<<B_ * (C_IN_ / GCH_), 512, 0, stream>>>(F, cand, xg);
    k_exact2 <<<B_ * NTILE_, 256, 0, stream>>>(xg, wt, bias, cand_feats);
    k_final  <<<B_, 512, 0, stream>>>(cand_feats, cand, sw, points, xout);
}